// Round 1
// baseline (331.412 us; speedup 1.0000x reference)
//
#include <hip/hip_runtime.h>

// Patcher: x (8,3,1024,1024) fp32, patch_size=24, stride=16, reflect pad m=4.
// Output: patches (B*nH*nW, 24*24, 3) fp32 + scalars nH, nW (=64).
// Pure gather/scatter, memory-bound. One thread per (patch, pixel) -> 3 channels.

constexpr int B_  = 8;
constexpr int C_  = 3;
constexpr int H_  = 1024;
constexpr int W_  = 1024;
constexpr int PS  = 24;   // patch_size
constexpr int STR = 16;   // stride
constexpr int M_  = 4;    // (PS - STR) / 2
constexpr int NH  = H_ / STR;          // 64
constexpr int NW  = W_ / STR;          // 64
constexpr int QTOT = PS * PS;          // 576
constexpr int NPQ  = B_ * NH * NW * QTOT;          // 18,874,368 threads
constexpr int PATCH_ELEMS_I = NPQ * C_;            // 56,623,104 (< 2^31)

__global__ __launch_bounds__(256) void patcher_kernel(
    const float* __restrict__ x, float* __restrict__ out, int tail)
{
    int t = blockIdx.x * blockDim.x + threadIdx.x;
    if (t < NPQ) {
        // decode: t = ((b*NH + ih)*NW + iw)*QTOT + pr*PS + pc
        int q  = t % QTOT;
        int p  = t / QTOT;
        int pc = q % PS;
        int pr = q / PS;
        int iw = p % NW;
        int t2 = p / NW;
        int ih = t2 % NH;
        int b  = t2 / NH;

        int h = ih * STR + pr - M_;
        int w = iw * STR + pc - M_;
        // reflect (pad=4 < H, single fold suffices); jnp 'reflect' => no edge repeat
        h = (h < 0) ? -h : ((h >= H_) ? (2 * H_ - 2 - h) : h);
        w = (w < 0) ? -w : ((w >= W_) ? (2 * W_ - 2 - w) : w);

        const float* base = x + ((b * C_) * H_ + h) * W_ + w;
        float v0 = base[0];
        float v1 = base[H_ * W_];
        float v2 = base[2 * H_ * W_];

        float* o = out + t * 3;
        o[0] = v0;
        o[1] = v1;
        o[2] = v2;
    }
    // trailing scalar outputs: nH, nW (both 64)
    if (t < tail) {
        out[PATCH_ELEMS_I + t] = 64.0f;
    }
}

extern "C" void kernel_launch(void* const* d_in, const int* in_sizes, int n_in,
                              void* d_out, int out_size, void* d_ws, size_t ws_size,
                              hipStream_t stream)
{
    const float* x = (const float*)d_in[0];
    float* out = (float*)d_out;

    int tail = out_size - PATCH_ELEMS_I;
    if (tail < 0) tail = 0;

    int threads = 256;
    int blocks = (NPQ + threads - 1) / threads;  // 73,728
    patcher_kernel<<<blocks, threads, 0, stream>>>(x, out, tail);
}

// Round 2
// 324.052 us; speedup vs baseline: 1.0227x; 1.0227x over previous
//
#include <hip/hip_runtime.h>

// Patcher: x (8,3,1024,1024) fp32, patch_size=24, stride=16, reflect pad m=4.
// Output: patches (32768, 576, 3) fp32 + scalars nH=nW=64.
// One workgroup per patch: float4 global loads -> planar LDS -> float4
// coalesced stores of the channel-interleaved output.

constexpr int PS  = 24;
constexpr int QTOT = PS * PS;                 // 576
constexpr int PATCH_F = QTOT * 3;             // 1728 floats per patch
constexpr int NPATCH = 8 * 64 * 64;           // 32768
constexpr int PATCH_ELEMS_I = NPATCH * PATCH_F; // 56,623,104
constexpr int NV = PATCH_F / 4;               // 432 float4 per patch

__global__ __launch_bounds__(256) void patcher_kernel(
    const float* __restrict__ x, float* __restrict__ out, int tail)
{
    __shared__ float lds[3 * QTOT];           // planar: [c][r][col], 6912 B

    int p  = blockIdx.x;                      // ((b*64 + ih)*64 + iw)
    int iw = p & 63;
    int ih = (p >> 6) & 63;
    int b  = p >> 12;
    int h0 = ih * 16 - 4;
    int w0 = iw * 16 - 4;
    int tid = threadIdx.x;

    const float* xb = x + (size_t)b * (3 * 1024 * 1024);

    bool edge = (ih == 0) | (ih == 63) | (iw == 0) | (iw == 63);
    if (!edge) {
        // interior: h0 in [12,988], w0 in [12,988] -> no reflect, 16B-aligned rows
        for (int j = tid; j < NV; j += 256) {
            int c   = j / 144;
            int rem = j - c * 144;
            int r   = rem / 6;
            int k   = rem - r * 6;
            const float4 v = *(const float4*)(xb + (c * 1024 + h0 + r) * 1024 + w0 + 4 * k);
            *(float4*)(&lds[c * QTOT + r * PS + 4 * k]) = v;
        }
    } else {
        for (int j = tid; j < NV; j += 256) {
            int c   = j / 144;
            int rem = j - c * 144;
            int r   = rem / 6;
            int k   = rem - r * 6;
            int h = h0 + r;
            h = (h < 0) ? -h : ((h > 1023) ? 2046 - h : h);
            const float* rowp = xb + (c * 1024 + h) * 1024;
#pragma unroll
            for (int e = 0; e < 4; ++e) {
                int w = w0 + 4 * k + e;
                w = (w < 0) ? -w : ((w > 1023) ? 2046 - w : w);
                lds[c * QTOT + r * PS + 4 * k + e] = rowp[w];
            }
        }
    }
    __syncthreads();

    float* ob = out + (size_t)p * PATCH_F;
    for (int j = tid; j < NV; j += 256) {
        int f = 4 * j;
        float4 v;
        float* vp = (float*)&v;
#pragma unroll
        for (int e = 0; e < 4; ++e) {
            int idx = f + e;              // output float index within patch
            int pix = idx / 3;            // pixel = pr*24+pc
            int c   = idx - pix * 3;
            vp[e] = lds[c * QTOT + pix];  // bank = pix & 31 -> <=2-way, free
        }
        *(float4*)(ob + f) = v;
    }

    // trailing scalar outputs nH, nW
    if (p == 0 && tid < tail) {
        out[(size_t)PATCH_ELEMS_I + tid] = 64.0f;
    }
}

extern "C" void kernel_launch(void* const* d_in, const int* in_sizes, int n_in,
                              void* d_out, int out_size, void* d_ws, size_t ws_size,
                              hipStream_t stream)
{
    const float* x = (const float*)d_in[0];
    float* out = (float*)d_out;

    int tail = out_size - PATCH_ELEMS_I;
    if (tail < 0) tail = 0;
    if (tail > 256) tail = 256;

    patcher_kernel<<<NPATCH, 256, 0, stream>>>(x, out, tail);
}